// Round 1
// baseline (918.968 us; speedup 1.0000x reference)
//
#include <hip/hip_runtime.h>
#include <cstdint>

#define T_    4096
#define HID_  2048
#define DH    128
#define NQ_   16
#define NKV_  4
#define QKVW  3072   // 2048 Q + 512 K + 512 V

typedef __attribute__((ext_vector_type(8))) short bf16x8;
typedef __attribute__((ext_vector_type(4))) float f32x4;
typedef __attribute__((ext_vector_type(4))) float f4;
typedef __attribute__((ext_vector_type(4))) short s4;

__device__ __forceinline__ short f2bf(float f) {
  union { float f; unsigned u; } x; x.f = f;
  unsigned r = x.u + 0x7fffu + ((x.u >> 16) & 1u);
  return (short)(r >> 16);
}
__device__ __forceinline__ float bf2f(short s) {
  return __uint_as_float(((unsigned)(unsigned short)s) << 16);
}

__device__ __forceinline__ void gload16(const void* g, void* l) {
  __builtin_amdgcn_global_load_lds(
      (const __attribute__((address_space(1))) unsigned*)g,
      (__attribute__((address_space(3))) unsigned*)l, 16, 0, 0);
}

#define MFMA16(a, b, c) __builtin_amdgcn_mfma_f32_16x16x32_bf16(a, b, c, 0, 0, 0)

// ---------------- fp32 -> bf16 conversion ----------------
__global__ void cvtk(const float* __restrict__ s, short* __restrict__ d, int n4) {
  int i = blockIdx.x * blockDim.x + threadIdx.x;
  const int stride = gridDim.x * blockDim.x;
  for (; i < n4; i += stride) {
    f4 v = ((const f4*)s)[i];
    s4 o;
    o[0] = f2bf(v[0]); o[1] = f2bf(v[1]); o[2] = f2bf(v[2]); o[3] = f2bf(v[3]);
    ((s4*)d)[i] = o;
  }
}

// ---------------- GEMM: C = A (MxK) * B^T, B stored (N,K) row-major ----------------
// 128x128 tile, BK=32, 4 waves in 2x2, global_load_lds staging (m97 structure).
template <int BF16OUT>
__global__ __launch_bounds__(256) void gemm_bt(const short* __restrict__ A,
                                               const short* __restrict__ B,
                                               void* __restrict__ Cp,
                                               int N, int K) {
  __shared__ short lA[128 * 32];
  __shared__ short lB[128 * 32];
  const int tid = threadIdx.x;
  const int lane = tid & 63;
  const int w = tid >> 6;
  const int wr = w >> 1, wc = w & 1;
  const int l15 = lane & 15, l4 = lane >> 4;
  f32x4 acc[4][4];
#pragma unroll
  for (int m = 0; m < 4; m++)
#pragma unroll
    for (int n = 0; n < 4; n++) acc[m][n] = f32x4{0.f, 0.f, 0.f, 0.f};

  const short* Ag = A + (size_t)blockIdx.x * 128 * K;
  const short* Bg = B + (size_t)blockIdx.y * 128 * K;

  for (int kt = 0; kt < K; kt += 32) {
#pragma unroll
    for (int i = 0; i < 2; ++i) {
      const int cb = i * 256 + w * 64;      // wave-uniform chunk base
      const int c = cb + lane;              // chunk of 8 bf16 (16B)
      const int row = c >> 2, eo = (c & 3) << 3;
      gload16(Ag + (size_t)row * K + kt + eo, &lA[cb * 8]);
      gload16(Bg + (size_t)row * K + kt + eo, &lB[cb * 8]);
    }
    __syncthreads();
    bf16x8 af[4], bfr[4];
#pragma unroll
    for (int m = 0; m < 4; m++)
      af[m] = *(const bf16x8*)&lA[(wr * 64 + m * 16 + l15) * 32 + l4 * 8];
#pragma unroll
    for (int n = 0; n < 4; n++)
      bfr[n] = *(const bf16x8*)&lB[(wc * 64 + n * 16 + l15) * 32 + l4 * 8];
#pragma unroll
    for (int m = 0; m < 4; m++)
#pragma unroll
      for (int n = 0; n < 4; n++)
        acc[m][n] = MFMA16(af[m], bfr[n], acc[m][n]);
    __syncthreads();
  }

  const int r0 = blockIdx.x * 128 + wr * 64;
  const int c0 = blockIdx.y * 128 + wc * 64;
#pragma unroll
  for (int m = 0; m < 4; m++)
#pragma unroll
    for (int n = 0; n < 4; n++)
#pragma unroll
      for (int r = 0; r < 4; r++) {
        const int row = r0 + m * 16 + l4 * 4 + r;
        const int col = c0 + n * 16 + l15;
        if (BF16OUT)
          ((short*)Cp)[(size_t)row * N + col] = f2bf(acc[m][n][r]);
        else
          ((float*)Cp)[(size_t)row * N + col] = acc[m][n][r];
      }
}

// ---------------- RoPE (in-place on bf16 qkv buffer, Q + K heads) ----------------
__global__ void rope_k(short* __restrict__ qkv, const int* __restrict__ pos) {
  const int row = blockIdx.x;
  const int sub = threadIdx.x >> 6;  // 0..3
  const int d = threadIdx.x & 63;
  const int head = blockIdx.y * 4 + sub;  // 0..19 : 16 Q heads then 4 K heads
  const int col0 = (head < NQ_) ? head * DH : HID_ + (head - NQ_) * DH;
  short* p = qkv + (size_t)row * QKVW + col0;
  const float fp = (float)pos[row];
  const float freq = fp * powf(10000.0f, -(float)d * (1.0f / 64.0f));
  const float sn = sinf(freq), cs = cosf(freq);
  const float x1 = bf2f(p[d]);
  const float x2 = bf2f(p[d + 64]);
  p[d] = f2bf(x1 * cs - x2 * sn);
  p[d + 64] = f2bf(x2 * cs + x1 * sn);
}

// ---------------- causal GQA flash attention ----------------
// grid (T/64, NQ). 4 waves/block, wave w owns q rows [qb*64+w*16, +16).
// KV tiles of 32 rows. K tile LDS padded stride 136; V^T stride 40; P stride 40.
#define KPAD 136
#define VPAD 40
#define PPAD 40

__global__ __launch_bounds__(256) void attn_k(const short* __restrict__ qkv,
                                              short* __restrict__ aout) {
  __shared__ short lK[32 * KPAD];
  __shared__ short lV[DH * VPAD];
  __shared__ short lP[4][16 * PPAD];
  const int qb = blockIdx.x, h = blockIdx.y, kvh = h >> 2;
  const int tid = threadIdx.x, lane = tid & 63, w = tid >> 6;
  const int l15 = lane & 15, l4 = lane >> 4;
  const int qrow0 = qb * 64 + w * 16;

  bf16x8 aq[4];
  {
    const short* qp = qkv + (size_t)(qrow0 + l15) * QKVW + h * DH + l4 * 8;
#pragma unroll
    for (int c = 0; c < 4; c++) aq[c] = *(const bf16x8*)(qp + c * 32);
  }
  f32x4 o[8];
#pragma unroll
  for (int i = 0; i < 8; i++) o[i] = f32x4{0.f, 0.f, 0.f, 0.f};
  float mrow[4] = {-3e38f, -3e38f, -3e38f, -3e38f};
  float lrow[4] = {0.f, 0.f, 0.f, 0.f};
  const int ntiles = qb * 2 + 2;
  const float sc = 0.08838834764831845f;  // 1/sqrt(128)

  for (int t = 0; t < ntiles; ++t) {
    const int kv0 = t * 32;
    // stage K (32x128) and V^T (128x32)
#pragma unroll
    for (int i = 0; i < 2; i++) {
      const int idx = i * 256 + tid;
      const int row = idx >> 4, e = (idx & 15) << 3;
      const short* kb = qkv + (size_t)(kv0 + row) * QKVW + HID_ + kvh * DH + e;
      bf16x8 kval = *(const bf16x8*)kb;
      *(bf16x8*)&lK[row * KPAD + e] = kval;
      const short* vb = qkv + (size_t)(kv0 + row) * QKVW + HID_ + NKV_ * DH + kvh * DH + e;
      bf16x8 vval = *(const bf16x8*)vb;
#pragma unroll
      for (int j = 0; j < 8; j++) lV[(e + j) * VPAD + row] = vval[j];
    }
    __syncthreads();

    // S = Q K^T  (two 16x16 col-tiles of the 16x32 score block)
    f32x4 s0 = {0.f, 0.f, 0.f, 0.f}, s1 = {0.f, 0.f, 0.f, 0.f};
#pragma unroll
    for (int c = 0; c < 4; c++) {
      bf16x8 bk0 = *(const bf16x8*)&lK[l15 * KPAD + c * 32 + l4 * 8];
      bf16x8 bk1 = *(const bf16x8*)&lK[(16 + l15) * KPAD + c * 32 + l4 * 8];
      s0 = MFMA16(aq[c], bk0, s0);
      s1 = MFMA16(aq[c], bk1, s1);
    }

    // online softmax
    float p0[4], p1[4], alpha[4];
#pragma unroll
    for (int r = 0; r < 4; r++) {
      const int qg = qrow0 + l4 * 4 + r;
      float v0 = (kv0 + l15 <= qg) ? s0[r] * sc : -3e38f;
      float v1 = (kv0 + 16 + l15 <= qg) ? s1[r] * sc : -3e38f;
      float mx = fmaxf(v0, v1);
      mx = fmaxf(mx, __shfl_xor(mx, 1));
      mx = fmaxf(mx, __shfl_xor(mx, 2));
      mx = fmaxf(mx, __shfl_xor(mx, 4));
      mx = fmaxf(mx, __shfl_xor(mx, 8));
      const float mnew = fmaxf(mrow[r], mx);
      alpha[r] = __expf(mrow[r] - mnew);
      p0[r] = __expf(v0 - mnew);
      p1[r] = __expf(v1 - mnew);
      float sm = p0[r] + p1[r];
      sm += __shfl_xor(sm, 1);
      sm += __shfl_xor(sm, 2);
      sm += __shfl_xor(sm, 4);
      sm += __shfl_xor(sm, 8);
      lrow[r] = lrow[r] * alpha[r] + sm;
      mrow[r] = mnew;
    }
#pragma unroll
    for (int dt = 0; dt < 8; dt++) {
#pragma unroll
      for (int r = 0; r < 4; r++) o[dt][r] *= alpha[r];
    }

    // P (D-layout) -> LDS -> A-layout
#pragma unroll
    for (int r = 0; r < 4; r++) {
      lP[w][(l4 * 4 + r) * PPAD + l15] = f2bf(p0[r]);
      lP[w][(l4 * 4 + r) * PPAD + 16 + l15] = f2bf(p1[r]);
    }
    __syncthreads();
    bf16x8 ap = *(const bf16x8*)&lP[w][l15 * PPAD + l4 * 8];
#pragma unroll
    for (int dt = 0; dt < 8; dt++) {
      bf16x8 bv = *(const bf16x8*)&lV[(dt * 16 + l15) * VPAD + l4 * 8];
      o[dt] = MFMA16(ap, bv, o[dt]);
    }
    __syncthreads();
  }

#pragma unroll
  for (int dt = 0; dt < 8; dt++)
#pragma unroll
    for (int r = 0; r < 4; r++) {
      const int row = qrow0 + l4 * 4 + r;
      const int col = h * DH + dt * 16 + l15;
      aout[(size_t)row * HID_ + col] = f2bf(o[dt][r] / lrow[r]);
    }
}

extern "C" void kernel_launch(void* const* d_in, const int* in_sizes, int n_in,
                              void* d_out, int out_size, void* d_ws, size_t ws_size,
                              hipStream_t stream) {
  const float* hs = (const float*)d_in[0];
  const float* wq = (const float*)d_in[1];
  const float* wk = (const float*)d_in[2];
  const float* wv = (const float*)d_in[3];
  const float* wo = (const float*)d_in[4];
  const int* pos = (const int*)d_in[5];
  float* out = (float*)d_out;

  const size_t SZ_HS = (size_t)T_ * HID_;       // 8388608
  const size_t SZ_WQ = (size_t)HID_ * HID_;     // 4194304
  const size_t SZ_WK = (size_t)(NKV_ * DH) * HID_;  // 1048576
  const size_t SZ_W1 = (size_t)QKVW * HID_;     // 6291456
  const size_t SZ_QKV = (size_t)T_ * QKVW;      // 12582912

  short* hs_bf = (short*)d_ws;
  short* w1_bf = hs_bf + SZ_HS;
  short* wo_bf = w1_bf + SZ_W1;
  short* qkv = wo_bf + SZ_WQ;
  short* attn = qkv + SZ_QKV;
  // total: 39,845,888 shorts = ~79.7 MB

  cvtk<<<1024, 256, 0, stream>>>(hs, hs_bf, (int)(SZ_HS / 4));
  cvtk<<<1024, 256, 0, stream>>>(wq, w1_bf, (int)(SZ_WQ / 4));
  cvtk<<<256, 256, 0, stream>>>(wk, w1_bf + SZ_WQ, (int)(SZ_WK / 4));
  cvtk<<<256, 256, 0, stream>>>(wv, w1_bf + SZ_WQ + SZ_WK, (int)(SZ_WK / 4));
  cvtk<<<1024, 256, 0, stream>>>(wo, wo_bf, (int)(SZ_WQ / 4));

  // QKV projection: (4096 x 2048) * (3072 x 2048)^T -> qkv bf16
  gemm_bt<1><<<dim3(T_ / 128, QKVW / 128), 256, 0, stream>>>(hs_bf, w1_bf, qkv, QKVW, HID_);

  // RoPE on Q (16 heads) + K (4 heads), in place
  rope_k<<<dim3(T_, 5), 256, 0, stream>>>(qkv, pos);

  // causal GQA flash attention -> attn bf16 (T, 2048)
  attn_k<<<dim3(T_ / 64, NQ_), 256, 0, stream>>>(qkv, attn);

  // output projection: (4096 x 2048) * (2048 x 2048)^T -> fp32 out
  gemm_bt<0><<<dim3(T_ / 128, HID_ / 128), 256, 0, stream>>>(attn, wo_bf, out, HID_, HID_);
}

// Round 2
// 465.617 us; speedup vs baseline: 1.9737x; 1.9737x over previous
//
#include <hip/hip_runtime.h>
#include <cstdint>

#define T_    4096
#define HID_  2048
#define DH    128
#define NQ_   16
#define NKV_  4
#define QKVW  3072   // 2048 Q + 512 K + 512 V

typedef __attribute__((ext_vector_type(8))) short bf16x8;
typedef __attribute__((ext_vector_type(4))) float f32x4;
typedef __attribute__((ext_vector_type(4))) float f4;
typedef __attribute__((ext_vector_type(4))) short s4;

__device__ __forceinline__ short f2bf(float f) {
  union { float f; unsigned u; } x; x.f = f;
  unsigned r = x.u + 0x7fffu + ((x.u >> 16) & 1u);
  return (short)(r >> 16);
}
__device__ __forceinline__ float bf2f(short s) {
  return __uint_as_float(((unsigned)(unsigned short)s) << 16);
}

__device__ __forceinline__ void gload16(const void* g, void* l) {
  __builtin_amdgcn_global_load_lds(
      (const __attribute__((address_space(1))) unsigned*)g,
      (__attribute__((address_space(3))) unsigned*)l, 16, 0, 0);
}

#define MFMA16(a, b, c) __builtin_amdgcn_mfma_f32_16x16x32_bf16(a, b, c, 0, 0, 0)

// ---------------- fp32 -> bf16 conversion ----------------
__global__ void cvtk(const float* __restrict__ s, short* __restrict__ d, int n4) {
  int i = blockIdx.x * blockDim.x + threadIdx.x;
  const int stride = gridDim.x * blockDim.x;
  for (; i < n4; i += stride) {
    f4 v = ((const f4*)s)[i];
    s4 o;
    o[0] = f2bf(v[0]); o[1] = f2bf(v[1]); o[2] = f2bf(v[2]); o[3] = f2bf(v[3]);
    ((s4*)d)[i] = o;
  }
}

// ---------------- GEMM: C = A (MxK) * B^T, B stored (N,K) row-major ----------------
template <int BF16OUT>
__global__ __launch_bounds__(256) void gemm_bt(const short* __restrict__ A,
                                               const short* __restrict__ B,
                                               void* __restrict__ Cp,
                                               int N, int K) {
  __shared__ short lA[128 * 32];
  __shared__ short lB[128 * 32];
  const int tid = threadIdx.x;
  const int lane = tid & 63;
  const int w = tid >> 6;
  const int wr = w >> 1, wc = w & 1;
  const int l15 = lane & 15, l4 = lane >> 4;
  f32x4 acc[4][4];
#pragma unroll
  for (int m = 0; m < 4; m++)
#pragma unroll
    for (int n = 0; n < 4; n++) acc[m][n] = f32x4{0.f, 0.f, 0.f, 0.f};

  const short* Ag = A + (size_t)blockIdx.x * 128 * K;
  const short* Bg = B + (size_t)blockIdx.y * 128 * K;

  for (int kt = 0; kt < K; kt += 32) {
#pragma unroll
    for (int i = 0; i < 2; ++i) {
      const int cb = i * 256 + w * 64;      // wave-uniform chunk base
      const int c = cb + lane;              // chunk of 8 bf16 (16B)
      const int row = c >> 2, eo = (c & 3) << 3;
      gload16(Ag + (size_t)row * K + kt + eo, &lA[cb * 8]);
      gload16(Bg + (size_t)row * K + kt + eo, &lB[cb * 8]);
    }
    __syncthreads();
    bf16x8 af[4], bfr[4];
#pragma unroll
    for (int m = 0; m < 4; m++)
      af[m] = *(const bf16x8*)&lA[(wr * 64 + m * 16 + l15) * 32 + l4 * 8];
#pragma unroll
    for (int n = 0; n < 4; n++)
      bfr[n] = *(const bf16x8*)&lB[(wc * 64 + n * 16 + l15) * 32 + l4 * 8];
#pragma unroll
    for (int m = 0; m < 4; m++)
#pragma unroll
      for (int n = 0; n < 4; n++)
        acc[m][n] = MFMA16(af[m], bfr[n], acc[m][n]);
    __syncthreads();
  }

  const int r0 = blockIdx.x * 128 + wr * 64;
  const int c0 = blockIdx.y * 128 + wc * 64;
#pragma unroll
  for (int m = 0; m < 4; m++)
#pragma unroll
    for (int n = 0; n < 4; n++)
#pragma unroll
      for (int r = 0; r < 4; r++) {
        const int row = r0 + m * 16 + l4 * 4 + r;
        const int col = c0 + n * 16 + l15;
        if (BF16OUT)
          ((short*)Cp)[(size_t)row * N + col] = f2bf(acc[m][n][r]);
        else
          ((float*)Cp)[(size_t)row * N + col] = acc[m][n][r];
      }
}

// ---------------- RoPE (in-place on bf16 qkv buffer, Q + K heads) ----------------
__global__ void rope_k(short* __restrict__ qkv, const int* __restrict__ pos) {
  const int row = blockIdx.x;
  const int sub = threadIdx.x >> 6;  // 0..3
  const int d = threadIdx.x & 63;
  const int head = blockIdx.y * 4 + sub;  // 0..19 : 16 Q heads then 4 K heads
  const int col0 = (head < NQ_) ? head * DH : HID_ + (head - NQ_) * DH;
  short* p = qkv + (size_t)row * QKVW + col0;
  const float fp = (float)pos[row];
  const float freq = fp * powf(10000.0f, -(float)d * (1.0f / 64.0f));
  const float sn = sinf(freq), cs = cosf(freq);
  const float x1 = bf2f(p[d]);
  const float x2 = bf2f(p[d + 64]);
  p[d] = f2bf(x1 * cs - x2 * sn);
  p[d + 64] = f2bf(x2 * cs + x1 * sn);
}

// ---------------- causal GQA flash attention (v2) ----------------
// 4 waves/block = the 4 Q heads of one KV group. Each wave owns 16 q rows.
// Work-paired q-blocks (qb, 255-qb) for balance. KV tile = 64 rows.
// K lds [64][128] + V^T lds [128][64], both XOR-swizzled on byte bits 4-6.
#define KVB  64
#define PPAD 72

// prefetch K/V tile (kv0) into kreg[4]/vreg[4]
#define PREFETCH(kv0)                                                           \
  {                                                                             \
    _Pragma("unroll") for (int i = 0; i < 4; i++) {                             \
      const int idx = i * 256 + tid;                                            \
      const int row = idx >> 4, e = (idx & 15) << 3;                            \
      kreg[i] = *(const bf16x8*)(kbase + (size_t)((kv0) + row) * QKVW + e);     \
    }                                                                           \
    _Pragma("unroll") for (int i = 0; i < 2; i++) {                             \
      const int idx = i * 256 + tid;                                            \
      const int rp = idx >> 4, e = (idx & 15) << 3;                             \
      vreg[2 * i] = *(const bf16x8*)(vbase + (size_t)((kv0) + 2 * rp) * QKVW + e);      \
      vreg[2 * i + 1] = *(const bf16x8*)(vbase + (size_t)((kv0) + 2 * rp + 1) * QKVW + e); \
    }                                                                           \
  }

__global__ __launch_bounds__(256) void attn_k(const short* __restrict__ qkv,
                                              short* __restrict__ aout) {
  __shared__ short lK[KVB * 128];
  __shared__ short lVT[128 * KVB];
  __shared__ short lP[4][16 * PPAD];
  // XCD-chunked remap: lin%8 -> XCD; each XCD gets one kvh's contiguous pairs
  const int lin = blockIdx.y * 128 + blockIdx.x;  // 0..511
  const int rl = (lin & 7) * 64 + (lin >> 3);     // bijective on 512
  const int kvh = rl >> 7;                        // 0..3
  const int pairi = rl & 127;                     // 0..127
  const int tid = threadIdx.x, lane = tid & 63, w = tid >> 6;
  const int l15 = lane & 15, l4 = lane >> 4;
  const int h = kvh * 4 + w;
  const float sc = 0.08838834764831845f;  // 1/sqrt(128)

  const short* kbase = qkv + HID_ + kvh * DH;
  const short* vbase = qkv + HID_ + NKV_ * DH + kvh * DH;

  for (int half = 0; half < 2; ++half) {
    const int qb = half ? (255 - pairi) : pairi;
    const int qrow0 = qb * 16;
    const int ntiles = qb / 4 + 1;

    bf16x8 aq[4];
    {
      const short* qp = qkv + (size_t)(qrow0 + l15) * QKVW + h * DH + l4 * 8;
#pragma unroll
      for (int c = 0; c < 4; c++) aq[c] = *(const bf16x8*)(qp + c * 32);
    }
    f32x4 o[8];
#pragma unroll
    for (int i = 0; i < 8; i++) o[i] = f32x4{0.f, 0.f, 0.f, 0.f};
    float mrow[4] = {-3e38f, -3e38f, -3e38f, -3e38f};
    float lrow[4] = {0.f, 0.f, 0.f, 0.f};

    bf16x8 kreg[4], vreg[4];
    PREFETCH(0);

    for (int t = 0; t < ntiles; ++t) {
      __syncthreads();  // all waves done reading previous tile's LDS
      // ---- store prefetched tile to LDS (swizzled) ----
#pragma unroll
      for (int i = 0; i < 4; i++) {
        const int idx = i * 256 + tid;
        const int row = idx >> 4, e = (idx & 15) << 3;
        const int sw = (((row >> 3) ^ row) & 7) << 4;
        *(bf16x8*)((char*)lK + row * 256 + ((e * 2) ^ sw)) = kreg[i];
      }
#pragma unroll
      for (int i = 0; i < 2; i++) {
        const int idx = i * 256 + tid;
        const int rp = idx >> 4, e = (idx & 15) << 3;
#pragma unroll
        for (int j = 0; j < 8; j++) {
          const int d = e + j;
          const int sw = (((d >> 3) ^ d) & 7) << 4;
          const unsigned pk = ((unsigned)(unsigned short)vreg[2 * i][j]) |
                              (((unsigned)(unsigned short)vreg[2 * i + 1][j]) << 16);
          *(unsigned*)((char*)lVT + d * 128 + ((rp * 4) ^ sw)) = pk;
        }
      }
      __syncthreads();  // staged tile visible
      if (t + 1 < ntiles) PREFETCH((t + 1) * KVB);  // overlap with compute

      // ---- QK^T ----
      f32x4 s[4];
#pragma unroll
      for (int ct = 0; ct < 4; ct++) s[ct] = f32x4{0.f, 0.f, 0.f, 0.f};
#pragma unroll
      for (int ct = 0; ct < 4; ct++) {
        const int row = ct * 16 + l15;
        const int sw = (((row >> 3) ^ row) & 7) << 4;
#pragma unroll
        for (int c = 0; c < 4; c++) {
          bf16x8 bk = *(const bf16x8*)((const char*)lK + row * 256 + ((c * 64 + l4 * 16) ^ sw));
          s[ct] = MFMA16(aq[c], bk, s[ct]);
        }
      }
      const int kv0 = t * KVB;

      // ---- online softmax ----
      float p[4][4], alpha[4];
#pragma unroll
      for (int r = 0; r < 4; r++) {
        const int qg = qrow0 + l4 * 4 + r;
        float mx = -3e38f;
#pragma unroll
        for (int ct = 0; ct < 4; ct++) {
          const float v = (kv0 + ct * 16 + l15 <= qg) ? s[ct][r] * sc : -3e38f;
          p[ct][r] = v;
          mx = fmaxf(mx, v);
        }
        mx = fmaxf(mx, __shfl_xor(mx, 1));
        mx = fmaxf(mx, __shfl_xor(mx, 2));
        mx = fmaxf(mx, __shfl_xor(mx, 4));
        mx = fmaxf(mx, __shfl_xor(mx, 8));
        const float mnew = fmaxf(mrow[r], mx);
        alpha[r] = __expf(mrow[r] - mnew);
        float sm = 0.f;
#pragma unroll
        for (int ct = 0; ct < 4; ct++) {
          p[ct][r] = __expf(p[ct][r] - mnew);
          sm += p[ct][r];
        }
        sm += __shfl_xor(sm, 1);
        sm += __shfl_xor(sm, 2);
        sm += __shfl_xor(sm, 4);
        sm += __shfl_xor(sm, 8);
        lrow[r] = lrow[r] * alpha[r] + sm;
        mrow[r] = mnew;
      }
#pragma unroll
      for (int dt = 0; dt < 8; dt++)
#pragma unroll
        for (int r = 0; r < 4; r++) o[dt][r] *= alpha[r];

      // ---- P (D-layout) -> per-wave LDS -> A-layout ----
#pragma unroll
      for (int r = 0; r < 4; r++)
#pragma unroll
        for (int ct = 0; ct < 4; ct++)
          lP[w][(l4 * 4 + r) * PPAD + ct * 16 + l15] = f2bf(p[ct][r]);
      const bf16x8 ap0 = *(const bf16x8*)&lP[w][l15 * PPAD + l4 * 8];
      const bf16x8 ap1 = *(const bf16x8*)&lP[w][l15 * PPAD + 32 + l4 * 8];

      // ---- PV ----
#pragma unroll
      for (int dt = 0; dt < 8; dt++) {
        const int row = dt * 16 + l15;
        const int sw = (((row >> 3) ^ row) & 7) << 4;
        const bf16x8 bv0 = *(const bf16x8*)((const char*)lVT + row * 128 + ((l4 * 16) ^ sw));
        const bf16x8 bv1 = *(const bf16x8*)((const char*)lVT + row * 128 + ((64 + l4 * 16) ^ sw));
        o[dt] = MFMA16(ap0, bv0, o[dt]);
        o[dt] = MFMA16(ap1, bv1, o[dt]);
      }
    }

    // ---- epilogue ----
    float rinv[4];
#pragma unroll
    for (int r = 0; r < 4; r++) rinv[r] = 1.0f / lrow[r];
#pragma unroll
    for (int dt = 0; dt < 8; dt++)
#pragma unroll
      for (int r = 0; r < 4; r++) {
        const int row = qrow0 + l4 * 4 + r;
        const int col = h * DH + dt * 16 + l15;
        aout[(size_t)row * HID_ + col] = f2bf(o[dt][r] * rinv[r]);
      }
  }
}

extern "C" void kernel_launch(void* const* d_in, const int* in_sizes, int n_in,
                              void* d_out, int out_size, void* d_ws, size_t ws_size,
                              hipStream_t stream) {
  const float* hs = (const float*)d_in[0];
  const float* wq = (const float*)d_in[1];
  const float* wk = (const float*)d_in[2];
  const float* wv = (const float*)d_in[3];
  const float* wo = (const float*)d_in[4];
  const int* pos = (const int*)d_in[5];
  float* out = (float*)d_out;

  const size_t SZ_HS = (size_t)T_ * HID_;
  const size_t SZ_WQ = (size_t)HID_ * HID_;
  const size_t SZ_WK = (size_t)(NKV_ * DH) * HID_;
  const size_t SZ_W1 = (size_t)QKVW * HID_;
  const size_t SZ_QKV = (size_t)T_ * QKVW;

  short* hs_bf = (short*)d_ws;
  short* w1_bf = hs_bf + SZ_HS;
  short* wo_bf = w1_bf + SZ_W1;
  short* qkv = wo_bf + SZ_WQ;
  short* attn = qkv + SZ_QKV;

  cvtk<<<1024, 256, 0, stream>>>(hs, hs_bf, (int)(SZ_HS / 4));
  cvtk<<<1024, 256, 0, stream>>>(wq, w1_bf, (int)(SZ_WQ / 4));
  cvtk<<<256, 256, 0, stream>>>(wk, w1_bf + SZ_WQ, (int)(SZ_WK / 4));
  cvtk<<<256, 256, 0, stream>>>(wv, w1_bf + SZ_WQ + SZ_WK, (int)(SZ_WK / 4));
  cvtk<<<1024, 256, 0, stream>>>(wo, wo_bf, (int)(SZ_WQ / 4));

  // QKV projection: (4096 x 2048) * (3072 x 2048)^T -> qkv bf16
  gemm_bt<1><<<dim3(T_ / 128, QKVW / 128), 256, 0, stream>>>(hs_bf, w1_bf, qkv, QKVW, HID_);

  // RoPE on Q (16 heads) + K (4 heads), in place
  rope_k<<<dim3(T_, 5), 256, 0, stream>>>(qkv, pos);

  // causal GQA flash attention -> attn bf16 (T, 2048)
  attn_k<<<dim3(128, 4), 256, 0, stream>>>(qkv, attn);

  // output projection: (4096 x 2048) * (2048 x 2048)^T -> fp32 out
  gemm_bt<0><<<dim3(T_ / 128, HID_ / 128), 256, 0, stream>>>(attn, wo_bf, out, HID_, HID_);
}

// Round 3
// 330.096 us; speedup vs baseline: 2.7839x; 1.4106x over previous
//
#include <hip/hip_runtime.h>
#include <cstdint>

#define T_    4096
#define HID_  2048
#define DH    128
#define NQ_   16
#define NKV_  4
#define QKVW  3072   // 2048 Q + 512 K + 512 V

typedef __attribute__((ext_vector_type(8))) short bf16x8;
typedef __attribute__((ext_vector_type(4))) float f32x4;
typedef __attribute__((ext_vector_type(16))) float f32x16;
typedef __attribute__((ext_vector_type(4))) float f4;
typedef __attribute__((ext_vector_type(4))) short s4;

__device__ __forceinline__ short f2bf(float f) {
  union { float f; unsigned u; } x; x.f = f;
  unsigned r = x.u + 0x7fffu + ((x.u >> 16) & 1u);
  return (short)(r >> 16);
}
__device__ __forceinline__ float bf2f(short s) {
  return __uint_as_float(((unsigned)(unsigned short)s) << 16);
}

__device__ __forceinline__ void gload16(const void* g, void* l) {
  __builtin_amdgcn_global_load_lds(
      (const __attribute__((address_space(1))) unsigned*)g,
      (__attribute__((address_space(3))) unsigned*)l, 16, 0, 0);
}

#define MFMA16(a, b, c) __builtin_amdgcn_mfma_f32_16x16x32_bf16(a, b, c, 0, 0, 0)
#define MFMA32(a, b, c) __builtin_amdgcn_mfma_f32_32x32x16_bf16(a, b, c, 0, 0, 0)

#define Z16 {0.f,0.f,0.f,0.f,0.f,0.f,0.f,0.f,0.f,0.f,0.f,0.f,0.f,0.f,0.f,0.f}

// ---------------- fp32 -> bf16 conversion ----------------
__global__ void cvtk(const float* __restrict__ s, short* __restrict__ d, int n4) {
  int i = blockIdx.x * blockDim.x + threadIdx.x;
  const int stride = gridDim.x * blockDim.x;
  for (; i < n4; i += stride) {
    f4 v = ((const f4*)s)[i];
    s4 o;
    o[0] = f2bf(v[0]); o[1] = f2bf(v[1]); o[2] = f2bf(v[2]); o[3] = f2bf(v[3]);
    ((s4*)d)[i] = o;
  }
}

// ---------------- GEMM: C = A (MxK) * B^T, B stored (N,K) row-major ----------------
template <int BF16OUT>
__global__ __launch_bounds__(256) void gemm_bt(const short* __restrict__ A,
                                               const short* __restrict__ B,
                                               void* __restrict__ Cp,
                                               int N, int K) {
  __shared__ short lA[128 * 32];
  __shared__ short lB[128 * 32];
  const int tid = threadIdx.x;
  const int lane = tid & 63;
  const int w = tid >> 6;
  const int wr = w >> 1, wc = w & 1;
  const int l15 = lane & 15, l4 = lane >> 4;
  f32x4 acc[4][4];
#pragma unroll
  for (int m = 0; m < 4; m++)
#pragma unroll
    for (int n = 0; n < 4; n++) acc[m][n] = f32x4{0.f, 0.f, 0.f, 0.f};

  const short* Ag = A + (size_t)blockIdx.x * 128 * K;
  const short* Bg = B + (size_t)blockIdx.y * 128 * K;

  for (int kt = 0; kt < K; kt += 32) {
#pragma unroll
    for (int i = 0; i < 2; ++i) {
      const int cb = i * 256 + w * 64;      // wave-uniform chunk base
      const int c = cb + lane;              // chunk of 8 bf16 (16B)
      const int row = c >> 2, eo = (c & 3) << 3;
      gload16(Ag + (size_t)row * K + kt + eo, &lA[cb * 8]);
      gload16(Bg + (size_t)row * K + kt + eo, &lB[cb * 8]);
    }
    __syncthreads();
    bf16x8 af[4], bfr[4];
#pragma unroll
    for (int m = 0; m < 4; m++)
      af[m] = *(const bf16x8*)&lA[(wr * 64 + m * 16 + l15) * 32 + l4 * 8];
#pragma unroll
    for (int n = 0; n < 4; n++)
      bfr[n] = *(const bf16x8*)&lB[(wc * 64 + n * 16 + l15) * 32 + l4 * 8];
#pragma unroll
    for (int m = 0; m < 4; m++)
#pragma unroll
      for (int n = 0; n < 4; n++)
        acc[m][n] = MFMA16(af[m], bfr[n], acc[m][n]);
    __syncthreads();
  }

  const int r0 = blockIdx.x * 128 + wr * 64;
  const int c0 = blockIdx.y * 128 + wc * 64;
#pragma unroll
  for (int m = 0; m < 4; m++)
#pragma unroll
    for (int n = 0; n < 4; n++)
#pragma unroll
      for (int r = 0; r < 4; r++) {
        const int row = r0 + m * 16 + l4 * 4 + r;
        const int col = c0 + n * 16 + l15;
        if (BF16OUT)
          ((short*)Cp)[(size_t)row * N + col] = f2bf(acc[m][n][r]);
        else
          ((float*)Cp)[(size_t)row * N + col] = acc[m][n][r];
      }
}

// ---------------- RoPE (in-place on bf16 qkv buffer, Q + K heads) ----------------
__global__ void rope_k(short* __restrict__ qkv, const int* __restrict__ pos) {
  const int row = blockIdx.x;
  const int sub = threadIdx.x >> 6;  // 0..3
  const int d = threadIdx.x & 63;
  const int head = blockIdx.y * 4 + sub;  // 0..19 : 16 Q heads then 4 K heads
  const int col0 = (head < NQ_) ? head * DH : HID_ + (head - NQ_) * DH;
  short* p = qkv + (size_t)row * QKVW + col0;
  const float fp = (float)pos[row];
  const float freq = fp * powf(10000.0f, -(float)d * (1.0f / 64.0f));
  const float sn = sinf(freq), cs = cosf(freq);
  const float x1 = bf2f(p[d]);
  const float x2 = bf2f(p[d + 64]);
  p[d] = f2bf(x1 * cs - x2 * sn);
  p[d + 64] = f2bf(x2 * cs + x1 * sn);
}

// ---------------- causal GQA flash attention (v3: swapped QK^T, 32x32 MFMA) ----------------
// 8 waves/block = 4 heads x 2 KV-splits (even/odd 64-row tiles). Each wave: 32 q-rows.
// Swapped S^T = mfma(K, Q^T): lane owns q-row (lane&31); softmax in-register.
// Paired q-blocks (i, 127-i): equal work, 256 blocks = 1/CU.
#define SCL2 0.127517432f  // (1/sqrt(128)) * log2(e)

// prefetch 2 tiles (even kv0=j*128, odd +64) into 8 regs
#define PRE(j)                                                                      \
  {                                                                                 \
    const int kv0e = (j) * 128, kv0o = (j) * 128 + 64;                              \
    _Pragma("unroll") for (int i = 0; i < 2; i++) {                                 \
      const int idx = i * 512 + tid;                                                \
      const int row = idx >> 4, e = (idx & 15) << 3;                                \
      kre[i] = *(const bf16x8*)(kbase + (size_t)(kv0e + row) * QKVW + e);           \
      kro[i] = *(const bf16x8*)(kbase + (size_t)(kv0o + row) * QKVW + e);           \
    }                                                                               \
    {                                                                               \
      const int rp = tid >> 4, e = (tid & 15) << 3;                                 \
      vre[0] = *(const bf16x8*)(vbase + (size_t)(kv0e + 2 * rp) * QKVW + e);        \
      vre[1] = *(const bf16x8*)(vbase + (size_t)(kv0e + 2 * rp + 1) * QKVW + e);    \
      vro[0] = *(const bf16x8*)(vbase + (size_t)(kv0o + 2 * rp) * QKVW + e);        \
      vro[1] = *(const bf16x8*)(vbase + (size_t)(kv0o + 2 * rp + 1) * QKVW + e);    \
    }                                                                               \
  }

__global__ __launch_bounds__(512) void attn_k(const short* __restrict__ qkv,
                                              short* __restrict__ aout) {
  __shared__ __align__(16) char smem[67584];  // 64KB staging (reused as O-merge) + 2KB m/l
  char* sKe = smem;                 // K even tile: [64 rows][256B], XOR-swizzled
  char* sKo = smem + 16384;
  char* sVe = smem + 32768;         // V^T even: [128 d][128B], XOR-swizzled
  char* sVo = smem + 49152;
  float* ml = (float*)(smem + 65536);  // [head][sp][2][32]

  const int lin = blockIdx.x;
  const int rl = (lin & 7) * 32 + (lin >> 3);  // XCD-chunked remap (bijective on 256)
  const int kvh = rl >> 6;
  const int pairi = rl & 63;
  const int tid = threadIdx.x, lane = tid & 63, w = tid >> 6;
  const int head = w & 3, sp = w >> 2;
  const int hi = lane >> 5, l31 = lane & 31;
  const int h = kvh * 4 + head;

  const short* kbase = qkv + HID_ + kvh * DH;
  const short* vbase = qkv + HID_ + NKV_ * DH + kvh * DH;
  const char* bK = sp ? sKo : sKe;
  const char* bV = sp ? sVo : sVe;

  for (int hf = 0; hf < 2; ++hf) {
    const int qb = hf ? (127 - pairi) : pairi;
    const int qrow0 = qb * 32;
    const int ntiles = qb / 2 + 1;
    const int nsuper = (ntiles + 1) >> 1;
    const int myq = qrow0 + l31;

    bf16x8 qf[8];
    {
      const short* qp = qkv + (size_t)myq * QKVW + h * DH + hi * 8;
#pragma unroll
      for (int c = 0; c < 8; c++) qf[c] = *(const bf16x8*)(qp + c * 16);
    }
    f32x16 o[4] = {Z16, Z16, Z16, Z16};
    float m = -3e38f, l = 0.f;

    bf16x8 kre[2], kro[2], vre[2], vro[2];
    PRE(0)

    for (int j = 0; j < nsuper; ++j) {
      __syncthreads();  // prev buffers consumed (and prev half's O-merge done)
      // ---- write both staged tiles to LDS (swizzled) ----
#pragma unroll
      for (int i = 0; i < 2; i++) {
        const int idx = i * 512 + tid;
        const int row = idx >> 4, e16 = (idx & 15) << 4;
        const int swz = (((row >> 3) ^ row) & 7) << 4;
        *(bf16x8*)(sKe + row * 256 + (e16 ^ swz)) = kre[i];
        *(bf16x8*)(sKo + row * 256 + (e16 ^ swz)) = kro[i];
      }
      {
        const int rp = tid >> 4, e = (tid & 15) << 3;
#pragma unroll
        for (int jj = 0; jj < 8; jj++) {
          const int d = e + jj;
          const int swz = (((d >> 3) ^ d) & 7) << 4;
          const unsigned pe = ((unsigned)(unsigned short)vre[0][jj]) |
                              (((unsigned)(unsigned short)vre[1][jj]) << 16);
          const unsigned po = ((unsigned)(unsigned short)vro[0][jj]) |
                              (((unsigned)(unsigned short)vro[1][jj]) << 16);
          *(unsigned*)(sVe + d * 128 + ((rp * 4) ^ swz)) = pe;
          *(unsigned*)(sVo + d * 128 + ((rp * 4) ^ swz)) = po;
        }
      }
      __syncthreads();
      if (j + 1 < nsuper) PRE(j + 1)

      const int t = 2 * j + sp;
      if (t < ntiles) {
        const int kv0 = t * 64;
        // ---- S^T = K Q^T : two 32x32 tiles over kv rows ----
        f32x16 s0 = Z16, s1 = Z16;
        const int sw0 = (((l31 >> 3) ^ l31) & 7) << 4;
        const int r1 = 32 + l31;
        const int sw1 = (((r1 >> 3) ^ r1) & 7) << 4;
#pragma unroll
        for (int c = 0; c < 8; c++) {
          const int co = c * 32 + hi * 16;
          const bf16x8 k0 = *(const bf16x8*)(bK + l31 * 256 + (co ^ sw0));
          const bf16x8 k1 = *(const bf16x8*)(bK + r1 * 256 + (co ^ sw1));
          s0 = MFMA32(k0, qf[c], s0);
          s1 = MFMA32(k1, qf[c], s1);
        }
        // ---- in-register online softmax (lane owns q-row l31, half the k's) ----
        float sv0[16], sv1[16];
        if (t == ntiles - 1) {
#pragma unroll
          for (int r = 0; r < 16; r++) {
            const int kk = (r & 3) + 8 * (r >> 2) + 4 * hi;
            sv0[r] = (kv0 + kk <= myq) ? s0[r] * SCL2 : -1e30f;
            sv1[r] = (kv0 + 32 + kk <= myq) ? s1[r] * SCL2 : -1e30f;
          }
        } else {
#pragma unroll
          for (int r = 0; r < 16; r++) {
            sv0[r] = s0[r] * SCL2;
            sv1[r] = s1[r] * SCL2;
          }
        }
        float mx[8];
#pragma unroll
        for (int r = 0; r < 8; r++)
          mx[r] = fmaxf(fmaxf(sv0[r], sv0[r + 8]), fmaxf(sv1[r], sv1[r + 8]));
#pragma unroll
        for (int st = 4; st > 0; st >>= 1)
#pragma unroll
          for (int r = 0; r < 4; r++)
            if (r < st) mx[r] = fmaxf(mx[r], mx[r + st]);
        float pm = fmaxf(mx[0], __shfl_xor(mx[0], 32));
        if (__any(pm > m + 11.5f)) {  // defer-max (T13)
          const float mn = fmaxf(m, pm);
          const float al = exp2f(m - mn);
          m = mn;
          l *= al;
#pragma unroll
          for (int r = 0; r < 16; r++) {
            const float ar = __shfl(al, (r & 3) + 8 * (r >> 2) + 4 * hi);
#pragma unroll
            for (int dt = 0; dt < 4; dt++) o[dt][r] *= ar;
          }
        }
        float pv0[16], pv1[16];
#pragma unroll
        for (int r = 0; r < 16; r++) {
          pv0[r] = exp2f(sv0[r] - m);
          pv1[r] = exp2f(sv1[r] - m);
        }
        float sum[8];
#pragma unroll
        for (int r = 0; r < 8; r++)
          sum[r] = (pv0[r] + pv0[r + 8]) + (pv1[r] + pv1[r + 8]);
#pragma unroll
        for (int st = 4; st > 0; st >>= 1)
#pragma unroll
          for (int r = 0; r < 4; r++)
            if (r < st) sum[r] = sum[r] + sum[r + st];
        l += sum[0] + __shfl_xor(sum[0], 32);

        // ---- P -> bf16 A-frags (pack + half-exchange), PV ----
        unsigned W0[8], W1[8];
#pragma unroll
        for (int i = 0; i < 8; i++) {
          W0[i] = ((unsigned)(unsigned short)f2bf(pv0[2 * i])) |
                  (((unsigned)(unsigned short)f2bf(pv0[2 * i + 1])) << 16);
          W1[i] = ((unsigned)(unsigned short)f2bf(pv1[2 * i])) |
                  (((unsigned)(unsigned short)f2bf(pv1[2 * i + 1])) << 16);
        }
#pragma unroll
        for (int kt = 0; kt < 2; kt++) {
#pragma unroll
          for (int hc = 0; hc < 2; hc++) {
            const int base = hc * 4;
            const unsigned a = kt ? W1[base] : W0[base];
            const unsigned c2 = kt ? W1[base + 1] : W0[base + 1];
            const unsigned b = kt ? W1[base + 2] : W0[base + 2];
            const unsigned d2 = kt ? W1[base + 3] : W0[base + 3];
            const unsigned as = __shfl_xor(a, 32);
            const unsigned cs = __shfl_xor(c2, 32);
            const unsigned bs = __shfl_xor(b, 32);
            const unsigned ds = __shfl_xor(d2, 32);
            union { unsigned u[4]; bf16x8 v; } fr;
            fr.u[0] = hi ? bs : a;
            fr.u[1] = hi ? ds : c2;
            fr.u[2] = hi ? b : as;
            fr.u[3] = hi ? d2 : cs;
            const int ko = kt * 64 + hc * 32 + hi * 16;
#pragma unroll
            for (int dt = 0; dt < 4; dt++) {
              const int row = dt * 32 + l31;
              const int swz = (((row >> 3) ^ row) & 7) << 4;
              const bf16x8 vf = *(const bf16x8*)(bV + row * 128 + (ko ^ swz));
              o[dt] = MFMA32(fr.v, vf, o[dt]);
            }
          }
        }
      }
    }

    // ---- merge the two KV-splits of each head, write out ----
    if (lane < 32) {
      ml[((head * 2 + sp) * 2) * 32 + lane] = m;
      ml[((head * 2 + sp) * 2 + 1) * 32 + lane] = l;
    }
    __syncthreads();
    const float mo = ml[((head * 2 + (1 - sp)) * 2) * 32 + l31];
    const float lo = ml[((head * 2 + (1 - sp)) * 2 + 1) * 32 + l31];
    const float M = fmaxf(m, mo);
    const float aown = exp2f(m - M);
    const float ltot = l * aown + lo * exp2f(mo - M);
#pragma unroll
    for (int r = 0; r < 16; r++) {
      const float ar = __shfl(aown, (r & 3) + 8 * (r >> 2) + 4 * hi);
#pragma unroll
      for (int dt = 0; dt < 4; dt++) o[dt][r] *= ar;
    }
    float* Ob = (float*)smem + head * 4096;  // [32 q][128 d]
    if (sp == 1) {
#pragma unroll
      for (int r = 0; r < 16; r++) {
        const int q = (r & 3) + 8 * (r >> 2) + 4 * hi;
#pragma unroll
        for (int dt = 0; dt < 4; dt++) Ob[q * 128 + dt * 32 + l31] = o[dt][r];
      }
    }
    __syncthreads();
    if (sp == 0) {
      const float ri = 1.0f / ltot;
#pragma unroll
      for (int r = 0; r < 16; r++) {
        const float rr = __shfl(ri, (r & 3) + 8 * (r >> 2) + 4 * hi);
        const int q = (r & 3) + 8 * (r >> 2) + 4 * hi;
#pragma unroll
        for (int dt = 0; dt < 4; dt++) {
          const float val = (o[dt][r] + Ob[q * 128 + dt * 32 + l31]) * rr;
          aout[(size_t)(qrow0 + q) * HID_ + h * DH + dt * 32 + l31] = f2bf(val);
        }
      }
    }
  }
}

extern "C" void kernel_launch(void* const* d_in, const int* in_sizes, int n_in,
                              void* d_out, int out_size, void* d_ws, size_t ws_size,
                              hipStream_t stream) {
  const float* hs = (const float*)d_in[0];
  const float* wq = (const float*)d_in[1];
  const float* wk = (const float*)d_in[2];
  const float* wv = (const float*)d_in[3];
  const float* wo = (const float*)d_in[4];
  const int* pos = (const int*)d_in[5];
  float* out = (float*)d_out;

  const size_t SZ_HS = (size_t)T_ * HID_;
  const size_t SZ_WQ = (size_t)HID_ * HID_;
  const size_t SZ_WK = (size_t)(NKV_ * DH) * HID_;
  const size_t SZ_W1 = (size_t)QKVW * HID_;
  const size_t SZ_QKV = (size_t)T_ * QKVW;

  short* hs_bf = (short*)d_ws;
  short* w1_bf = hs_bf + SZ_HS;
  short* wo_bf = w1_bf + SZ_W1;
  short* qkv = wo_bf + SZ_WQ;
  short* attn = qkv + SZ_QKV;

  cvtk<<<1024, 256, 0, stream>>>(hs, hs_bf, (int)(SZ_HS / 4));
  cvtk<<<1024, 256, 0, stream>>>(wq, w1_bf, (int)(SZ_WQ / 4));
  cvtk<<<256, 256, 0, stream>>>(wk, w1_bf + SZ_WQ, (int)(SZ_WK / 4));
  cvtk<<<256, 256, 0, stream>>>(wv, w1_bf + SZ_WQ + SZ_WK, (int)(SZ_WK / 4));
  cvtk<<<1024, 256, 0, stream>>>(wo, wo_bf, (int)(SZ_WQ / 4));

  // QKV projection: (4096 x 2048) * (3072 x 2048)^T -> qkv bf16
  gemm_bt<1><<<dim3(T_ / 128, QKVW / 128), 256, 0, stream>>>(hs_bf, w1_bf, qkv, QKVW, HID_);

  // RoPE on Q (16 heads) + K (4 heads), in place
  rope_k<<<dim3(T_, 5), 256, 0, stream>>>(qkv, pos);

  // causal GQA flash attention -> attn bf16 (T, 2048)
  attn_k<<<dim3(256), 512, 0, stream>>>(qkv, attn);

  // output projection: (4096 x 2048) * (2048 x 2048)^T -> fp32 out
  gemm_bt<0><<<dim3(T_ / 128, HID_ / 128), 256, 0, stream>>>(attn, wo_bf, out, HID_, HID_);
}